// Round 1
// 102.529 us; speedup vs baseline: 1.0124x; 1.0124x over previous
//
#include <hip/hip_runtime.h>

// Problem constants (reference: B,S,D,H = 2,2048,1024,16)
#define BB 2
#define SS 2048
#define DD 1024

// The attention mask keeps only key index 0 => softmax is exactly one-hot on
// key 0 (exp(-1e9) underflows to 0 in fp32). The whole block reduces to:
//   Vrow[b,f] = sum_d v[b,0,d] * Wv[f,d]
//   yvec[b,e] = sum_f Vrow[b,f] * Wo[e,f]
//   out[b,s,e] = yvec[b,e]   (broadcast over s; q,k,Wq,Wk unused)

// One wave (64 lanes) computes one weight row r, dotted against BOTH batch
// vectors simultaneously -> W is fetched exactly once (4 MB, not 8 MB).
// x0/x1 are 4 KB each and L2-hot after the first wave touches them.
__global__ void __launch_bounds__(256)
matvec_rows2(const float* __restrict__ W,    // [DD, DD] row-major
             const float* __restrict__ x0,   // batch-0 vector, DD floats
             const float* __restrict__ x1,   // batch-1 vector, DD floats
             float* __restrict__ y) {        // [BB, DD]
    const int lane = threadIdx.x & 63;
    const int wave = threadIdx.x >> 6;
    const int r = blockIdx.x * (blockDim.x >> 6) + wave;  // [0, DD)

    const float* __restrict__ wr = W + r * DD;

    float a0 = 0.f, a1 = 0.f;
    // 1024 = 4 iters * 64 lanes * 4 floats, fully coalesced float4 loads
    #pragma unroll
    for (int i = 0; i < 4; ++i) {
        const int c = (i * 64 + lane) * 4;
        const float4 wv = *(const float4*)(wr + c);
        const float4 xa = *(const float4*)(x0 + c);
        const float4 xb = *(const float4*)(x1 + c);
        a0 += wv.x * xa.x + wv.y * xa.y + wv.z * xa.z + wv.w * xa.w;
        a1 += wv.x * xb.x + wv.y * xb.y + wv.z * xb.z + wv.w * xb.w;
    }
    // 64-lane butterfly reduce (both accumulators share the shuffle passes)
    #pragma unroll
    for (int off = 32; off > 0; off >>= 1) {
        a0 += __shfl_down(a0, off, 64);
        a1 += __shfl_down(a1, off, 64);
    }

    if (lane == 0) {
        y[r]      = a0;   // b = 0
        y[DD + r] = a1;   // b = 1
    }
}

// out[b,s,e] = yvec[b,e]; float4-vectorized broadcast write (fully coalesced).
__global__ void __launch_bounds__(256)
broadcast_out(const float4* __restrict__ yvec4,  // [BB, DD/4]
              float4* __restrict__ out4) {       // [BB, SS, DD/4]
    const int i = blockIdx.x * blockDim.x + threadIdx.x;  // [0, BB*SS*DD/4)
    const int e4 = i & 255;           // DD/4 = 256
    const int b = i >> 19;            // / (SS * DD/4) = / 524288
    out4[i] = yvec4[(b << 8) + e4];
}

extern "C" void kernel_launch(void* const* d_in, const int* in_sizes, int n_in,
                              void* d_out, int out_size, void* d_ws, size_t ws_size,
                              hipStream_t stream) {
    // inputs: 0=q 1=k 2=v 3=Wq 4=Wk 5=Wv 6=Wo (all float32)
    const float* v  = (const float*)d_in[2];
    const float* Wv = (const float*)d_in[5];
    const float* Wo = (const float*)d_in[6];
    float* out = (float*)d_out;

    float* Vrow = (float*)d_ws;              // [BB, DD]
    float* yvec = Vrow + BB * DD;            // [BB, DD]

    // 1) Vrow[b,f] = v[b,0,:] . Wv[f,:]   (DD waves, 4 waves/block, both b at once)
    matvec_rows2<<<DD / 4, 256, 0, stream>>>(Wv, v, v + (size_t)SS * DD, Vrow);
    // 2) yvec[b,e] = Vrow[b,:] . Wo[e,:]
    matvec_rows2<<<DD / 4, 256, 0, stream>>>(Wo, Vrow, Vrow + DD, yvec);
    // 3) broadcast to all sequence positions
    const int n4 = BB * SS * DD / 4;         // 1,048,576 float4s
    broadcast_out<<<n4 / 256, 256, 0, stream>>>((const float4*)yvec, (float4*)out);
}